// Round 2
// baseline (427.362 us; speedup 1.0000x reference)
//
#include <hip/hip_runtime.h>

typedef __attribute__((ext_vector_type(8))) short short8;
typedef __attribute__((ext_vector_type(4))) float f32x4;

// fp32 -> bf16 bits, round-to-nearest-even
__device__ __forceinline__ short f2bf(float f) {
    unsigned u = __builtin_bit_cast(unsigned, f);
    u += 0x7fffu + ((u >> 16) & 1u);
    return (short)(u >> 16);
}

// Kernel 1: W_eff = sum_r s_r * W_r, stored TRANSPOSED as bf16: WT[n*128+k].
__global__ void weff_kernel(const float* __restrict__ W,
                            const float* __restrict__ S,
                            short* __restrict__ WT) {
    int idx = blockIdx.x * 256 + threadIdx.x;   // 0..16383 == k*128 + n
    int k = idx >> 7;
    int n = idx & 127;
    float acc = 0.f;
#pragma unroll
    for (int r = 0; r < 8; ++r) acc += S[r] * W[r * 16384 + idx];
    WT[n * 128 + k] = f2bf(acc);
}

// Kernel 2: C[M,128] = A[M,128] @ W_eff[128,128], bf16 MFMA, fp32 accumulate.
// Block: 256 threads = 4 waves; 128 rows/block (32 rows/wave), full K=128.
// B-frag LDS reads feed 2 MFMAs each (2 row-fragments share each bfrag).
// Epilogue bounces C through LDS (reusing the B buffer) for coalesced
// global_store_dwordx4.
#define BSTRIDE 136   // shorts: 128 + 8 pad -> 16B-aligned rows, uniform 8 dw/bank on b128
#define CSTRIDE 132   // floats: 128 + 4 pad -> 16B-aligned rows, 2-way (free) banking on writes
#define SMEM_BYTES 34816  // max(128*BSTRIDE*2 = 34816, 4*16*CSTRIDE*4 = 33792)

__global__ __launch_bounds__(256, 4) void gemm_kernel(const float* __restrict__ A,
                                                      const short* __restrict__ WT,
                                                      float* __restrict__ C,
                                                      int N) {
    __shared__ __align__(16) unsigned char smem[SMEM_BYTES];
    short* Bs = (short*)smem;

    int tid = threadIdx.x;
    // Stage W_eff^T (bf16) into padded LDS: 2048 x 16B chunks, coalesced.
#pragma unroll
    for (int it = 0; it < 8; ++it) {
        int chunk = it * 256 + tid;            // 0..2047
        int n  = chunk >> 4;                   // row of WT (output col)
        int kc = chunk & 15;                   // which 8-element k chunk
        *(short8*)&Bs[n * BSTRIDE + kc * 8] = ((const short8*)WT)[chunk];
    }
    __syncthreads();

    int wave = tid >> 6;
    int lane = tid & 63;
    int quad = lane >> 4;
    int r16  = lane & 15;

    long m0 = (long)blockIdx.x * 128 + wave * 32;

    const float* arow[2];
#pragma unroll
    for (int mf = 0; mf < 2; ++mf) {
        long r = m0 + mf * 16 + r16;
        long rc = r < N ? r : (long)(N - 1);   // clamp: junk rows never stored
        arow[mf] = A + rc * 128;
    }

    f32x4 acc[2][8];
#pragma unroll
    for (int mf = 0; mf < 2; ++mf)
#pragma unroll
        for (int t = 0; t < 8; ++t) acc[mf][t] = (f32x4)(0.f);

#pragma unroll
    for (int kk = 0; kk < 4; ++kk) {
        int k = kk * 32 + quad * 8;            // A frag: A[m][k..k+7]
        short8 af[2];
#pragma unroll
        for (int mf = 0; mf < 2; ++mf) {
            float4 p = *(const float4*)(arow[mf] + k);
            float4 q = *(const float4*)(arow[mf] + k + 4);
            af[mf][0] = f2bf(p.x); af[mf][1] = f2bf(p.y);
            af[mf][2] = f2bf(p.z); af[mf][3] = f2bf(p.w);
            af[mf][4] = f2bf(q.x); af[mf][5] = f2bf(q.y);
            af[mf][6] = f2bf(q.z); af[mf][7] = f2bf(q.w);
        }
#pragma unroll
        for (int t = 0; t < 8; ++t) {
            // B frag: B[k..k+7][n = t*16 + r16] == WT[(t*16+r16)][k..k+7]
            short8 bf = *(const short8*)&Bs[(t * 16 + r16) * BSTRIDE + k];
            acc[0][t] = __builtin_amdgcn_mfma_f32_16x16x32_bf16(af[0], bf, acc[0][t], 0, 0, 0);
            acc[1][t] = __builtin_amdgcn_mfma_f32_16x16x32_bf16(af[1], bf, acc[1][t], 0, 0, 0);
        }
    }

    // All waves done reading Bs -> reuse the buffer as per-wave C bounce slots.
    __syncthreads();
    float* Cs = (float*)smem + wave * 16 * CSTRIDE;   // 8448 B per wave slot

#pragma unroll
    for (int mf = 0; mf < 2; ++mf) {
        // C/D layout: col = t*16 + r16, row = quad*4 + reg (verified in R1).
        // Same-wave LDS ops are processed in order; slots are wave-private,
        // so no barrier needed between mf passes.
#pragma unroll
        for (int reg = 0; reg < 4; ++reg)
#pragma unroll
            for (int t = 0; t < 8; ++t)
                Cs[(quad * 4 + reg) * CSTRIDE + t * 16 + r16] = acc[mf][t][reg];

        long gm0 = m0 + mf * 16;
#pragma unroll
        for (int j = 0; j < 8; ++j) {
            int c  = j * 64 + lane;            // 0..511: 16 rows x 32 float4-chunks
            int rl = c >> 5;                   // local row 0..15
            int c4 = (c & 31) * 4;             // col offset in floats
            f32x4 v = *(f32x4*)&Cs[rl * CSTRIDE + c4];
            long row = gm0 + rl;
            if (row < N) *(f32x4*)(C + row * 128 + c4) = v;
        }
    }
}

extern "C" void kernel_launch(void* const* d_in, const int* in_sizes, int n_in,
                              void* d_out, int out_size, void* d_ws, size_t ws_size,
                              hipStream_t stream) {
    const float* inputs = (const float*)d_in[0];     // [N,128] fp32
    const float* W      = (const float*)d_in[1];     // [8,128,128] fp32
    const float* S      = (const float*)d_in[2];     // [8,1] fp32
    float* out = (float*)d_out;                      // [N,128] fp32
    short* WT  = (short*)d_ws;                       // [128,128] bf16 (W_eff^T)

    int N = in_sizes[0] / 128;

    weff_kernel<<<64, 256, 0, stream>>>(W, S, WT);
    int grid = (N + 127) / 128;
    gemm_kernel<<<grid, 256, 0, stream>>>(inputs, WT, out, N);
}